// Round 6
// baseline (116.017 us; speedup 1.0000x reference)
//
#include <hip/hip_runtime.h>
#include <stdint.h>

#define N_SEQ 4096

typedef float f32x4 __attribute__((ext_vector_type(4)));
typedef float f32x2 __attribute__((ext_vector_type(2)));
typedef unsigned short u16x8 __attribute__((ext_vector_type(8)));
typedef unsigned short u16x4 __attribute__((ext_vector_type(4)));
typedef unsigned int u32x2 __attribute__((ext_vector_type(2)));
typedef __bf16 bf16x8 __attribute__((ext_vector_type(8)));

static __device__ __forceinline__ float bf2f(unsigned short u) {
    unsigned v = ((unsigned)u) << 16;
    return __builtin_bit_cast(float, v);
}

// ---------------- Kernel 1: QKV projection (fp32 GEMM, bf16 out) ----------------
// (round-4 proven version, verbatim)
// x[16384][128] @ Wq[128][384] + bq.
// Q  -> natural [bh][n][32], PRE-SCALED by SL = (1/sqrt(128))*log2(e)
// KF -> fragment-ready: KF[((bh*64+t)*4+ct)*512 + l*8 + i] = K[bh][64t+(l&15)+16ct][(l>>4)*8+i]
// VF -> fragment-ready, kv LINEAR: VF[(((bh*64+t)*2+kk)*2+dt)*512 + l*8 + i]
//       = V[bh][64t+kv][(l&15)+16dt], kv = kk*32 + (l>>4)*8 + i
__global__ __launch_bounds__(256) void qkv_kernel(
    const float* __restrict__ x, const float* __restrict__ Wq,
    const float* __restrict__ bq, unsigned short* __restrict__ Qo,
    unsigned short* __restrict__ KFo, unsigned short* __restrict__ VFo)
{
    __shared__ __align__(16) float xT[128][36];   // [k][row]
    const int tid = threadIdx.x;
    const long r0 = (long)blockIdx.x * 32;
    const float SL = (float)(0.08838834764831845 * 1.4426950408889634);
    #pragma unroll
    for (int i = 0; i < 4; ++i) {
        int idx = i * 256 + tid;                   // 1024 float4 tiles
        int row = idx >> 5, kc = (idx & 31) * 4;
        f32x4 v = *(const f32x4*)&x[(r0 + row) * 128 + kc];
        xT[kc + 0][row] = v[0]; xT[kc + 1][row] = v[1];
        xT[kc + 2][row] = v[2]; xT[kc + 3][row] = v[3];
    }
    __syncthreads();
    const int r8 = (tid >> 6) * 8;    // 8-row group
    const int c6 = (tid & 63) * 6;    // 6 consecutive cols
    float acc[6][8];
    #pragma unroll
    for (int j = 0; j < 6; ++j)
        #pragma unroll
        for (int r = 0; r < 8; ++r) acc[j][r] = 0.f;

    for (int k = 0; k < 128; ++k) {
        f32x4 a0 = *(const f32x4*)&xT[k][r8];      // wave-uniform broadcast
        f32x4 a1 = *(const f32x4*)&xT[k][r8 + 4];
        float xr[8] = {a0[0],a0[1],a0[2],a0[3],a1[0],a1[1],a1[2],a1[3]};
        float wv[6];
        #pragma unroll
        for (int u = 0; u < 3; ++u) {
            f32x2 wp = *(const f32x2*)&Wq[k * 384 + c6 + 2 * u];
            wv[2*u] = wp[0]; wv[2*u+1] = wp[1];
        }
        #pragma unroll
        for (int j = 0; j < 6; ++j)
            #pragma unroll
            for (int r = 0; r < 8; ++r) acc[j][r] = fmaf(xr[r], wv[j], acc[j][r]);
    }
    #pragma unroll
    for (int j = 0; j < 6; ++j) {
        int col = c6 + j;
        int h = col / 96, rem = col % 96;
        int d = rem / 3, s = rem % 3;
        float bias = bq[col];
        #pragma unroll
        for (int r = 0; r < 8; ++r) {
            long n = r0 + r8 + r;
            int bb = (int)(n >> 12), nn = (int)(n & 4095);
            int bh = bb * 4 + h;
            int t = nn >> 6, kvi = nn & 63;
            float val = acc[j][r] + bias;
            if (s == 0) {
                unsigned short bits = __builtin_bit_cast(unsigned short, (__bf16)(val * SL));
                Qo[((long)bh * 4096 + nn) * 32 + d] = bits;
            } else if (s == 1) {
                unsigned short bits = __builtin_bit_cast(unsigned short, (__bf16)val);
                int ct = kvi >> 4, lo16 = kvi & 15;
                int gg = d >> 3, ii = d & 7;
                int l = gg * 16 + lo16;
                KFo[(long)(((bh * 64 + t) * 4 + ct) * 512) + l * 8 + ii] = bits;
            } else {
                unsigned short bits = __builtin_bit_cast(unsigned short, (__bf16)val);
                // kv LINEAR order (identity pos) to match attn's P-read chunks
                int kk = kvi >> 5, lg = (kvi >> 3) & 3, ii = kvi & 7;
                int l = lg * 16 + (d & 15);
                int dt = d >> 4;
                VFo[(long)((((bh * 64 + t) * 2 + kk) * 2 + dt) * 512) + l * 8 + ii] = bits;
            }
        }
    }
}

// ---------------- Kernel 2: flash attention, 16 q-rows/wave, 4 blocks/CU ----------------
// Numerics identical to round-4 proven kernel (exp2 + 0x8000 + v_perm pack);
// only the parallelism layout changed (1 q-tile/wave, 1024 blocks).
#define MFMA16 __builtin_amdgcn_mfma_f32_16x16x32_bf16

__global__ __launch_bounds__(256, 4) void attn_kernel(
    const unsigned short* __restrict__ Q, const unsigned short* __restrict__ KF,
    const unsigned short* __restrict__ VF, unsigned short* __restrict__ AO)
{
    __shared__ __align__(16) unsigned short P_lds[4][2][1024]; // per-wave dbuf P (16x64)

    const int tid = threadIdx.x, lane = tid & 63, w = tid >> 6;
    const int g = lane >> 4, lo = lane & 15;

    // bijective XCD swizzle over 1024 blocks: each XCD owns 2 consecutive bh
    const int bid = blockIdx.x;
    const int vid = (bid & 7) * 128 + (bid >> 3);
    const int qi = vid & 63, bh = vid >> 6;
    const int q0 = qi * 64 + w * 16;

    bf16x8 qf;
    {
        const unsigned short* p = Q + ((long)bh * 4096 + q0 + lo) * 32 + g * 8;
        qf = __builtin_bit_cast(bf16x8, *(const u16x8*)p);
    }
    bf16x8 onesf;
    {
        u16x8 ou = {0x3F80,0x3F80,0x3F80,0x3F80,0x3F80,0x3F80,0x3F80,0x3F80};
        onesf = __builtin_bit_cast(bf16x8, ou);
    }
    const f32x4 zf = {0.f, 0.f, 0.f, 0.f};
    f32x4 o_[2] = {zf, zf};
    f32x4 ls    = zf;

    // P LDS layout: P[q][kv] at short-offset q*64 + (((kv>>3) ^ (q&7))*8) + (kv&7)
    // Swapped QK^T D-layout: s_[ct][j] = S[q = lo][kv = 16ct + 4g + j]
    int woff[4], roff[2];
    #pragma unroll
    for (int ct = 0; ct < 4; ++ct) {
        int kvb = 16 * ct + 4 * g;
        woff[ct] = lo * 64 + (((kvb >> 3) ^ (lo & 7)) * 8) + ((kvb >> 2) & 1) * 4;
    }
    #pragma unroll
    for (int kk = 0; kk < 2; ++kk)
        roff[kk] = lo * 64 + ((((4 * kk) + g) ^ (lo & 7)) * 8);

    unsigned short* B0 = &P_lds[w][0][0];
    unsigned short* B1 = &P_lds[w][1][0];

    const u16x8* kp = (const u16x8*)KF + (long)bh * 64 * 256 + lane; // 256 u16x8/tile
    const u16x8* vp = (const u16x8*)VF + (long)bh * 64 * 256 + lane;

    u16x8 K0[4], K1[4], V0[4], V1[4];
    #pragma unroll
    for (int i = 0; i < 4; ++i) K0[i] = kp[i * 64];   // K(0)
    kp += 256;

// iteration t: prefetch K(t+1)->KN, V(t)->VC; read P(t-1) from BR; QK(t) with KC;
// PV(t-1) with VP; softmax(t) -> BW.
#define BODY(KC, KN, VP, VC, BW, BR, DOPV) do {                                \
    _Pragma("unroll")                                                          \
    for (int i = 0; i < 4; ++i) KN[i] = kp[i * 64];                            \
    kp += 256;                                                                 \
    _Pragma("unroll")                                                          \
    for (int i = 0; i < 4; ++i) VC[i] = vp[i * 64];                            \
    vp += 256;                                                                 \
    u16x8 pa_[2];                                                              \
    if (DOPV) {                                                                \
        _Pragma("unroll")                                                      \
        for (int kk = 0; kk < 2; ++kk)                                         \
            pa_[kk] = *(const u16x8*)&BR[roff[kk]];                            \
    }                                                                          \
    f32x4 s_[4];                                                               \
    _Pragma("unroll")                                                          \
    for (int ct = 0; ct < 4; ++ct) {                                           \
        bf16x8 kfr = __builtin_bit_cast(bf16x8, KC[ct]);                       \
        s_[ct] = MFMA16(kfr, qf, zf, 0, 0, 0);                                 \
    }                                                                          \
    if (DOPV) {                                                                \
        _Pragma("unroll")                                                      \
        for (int kk = 0; kk < 2; ++kk) {                                       \
            bf16x8 paf = __builtin_bit_cast(bf16x8, pa_[kk]);                  \
            ls = MFMA16(paf, onesf, ls, 0, 0, 0);                              \
            o_[0] = MFMA16(paf, __builtin_bit_cast(bf16x8, VP[kk*2+0]),        \
                           o_[0], 0, 0, 0);                                    \
            o_[1] = MFMA16(paf, __builtin_bit_cast(bf16x8, VP[kk*2+1]),        \
                           o_[1], 0, 0, 0);                                    \
        }                                                                      \
    }                                                                          \
    _Pragma("unroll")                                                          \
    for (int ct = 0; ct < 4; ++ct) {                                           \
        unsigned b0 = __builtin_bit_cast(unsigned,                             \
            __builtin_amdgcn_exp2f(s_[ct][0])) + 0x8000u;                      \
        unsigned b1 = __builtin_bit_cast(unsigned,                             \
            __builtin_amdgcn_exp2f(s_[ct][1])) + 0x8000u;                      \
        unsigned b2 = __builtin_bit_cast(unsigned,                             \
            __builtin_amdgcn_exp2f(s_[ct][2])) + 0x8000u;                      \
        unsigned b3 = __builtin_bit_cast(unsigned,                             \
            __builtin_amdgcn_exp2f(s_[ct][3])) + 0x8000u;                      \
        u32x2 wv_;                                                             \
        wv_[0] = __builtin_amdgcn_perm(b1, b0, 0x07060302u);                   \
        wv_[1] = __builtin_amdgcn_perm(b3, b2, 0x07060302u);                   \
        *(u16x4*)&BW[woff[ct]] = __builtin_bit_cast(u16x4, wv_);               \
    }                                                                          \
    __builtin_amdgcn_sched_barrier(0);                                         \
} while (0)

    BODY(K0, K1, V1, V0, B0, B1, 0);            // t = 0 (no PV yet)
    #pragma unroll 1
    for (int t = 1; t < 63; t += 2) {
        BODY(K1, K0, V0, V1, B1, B0, 1);        // odd t
        BODY(K0, K1, V1, V0, B0, B1, 1);        // even t+1
    }
    BODY(K1, K0, V0, V1, B1, B0, 1);            // t = 63 (prefetch overshoots: in-bounds ws, unused)
#undef BODY

    // final PV(63): P in B1, V(63) in V1
    #pragma unroll
    for (int kk = 0; kk < 2; ++kk) {
        bf16x8 paf = __builtin_bit_cast(bf16x8, *(const u16x8*)&B1[roff[kk]]);
        ls = MFMA16(paf, onesf, ls, 0, 0, 0);
        o_[0] = MFMA16(paf, __builtin_bit_cast(bf16x8, V1[kk*2+0]), o_[0], 0, 0, 0);
        o_[1] = MFMA16(paf, __builtin_bit_cast(bf16x8, V1[kk*2+1]), o_[1], 0, 0, 0);
    }

    // epilogue: AO[b][n][h*32+d] bf16 ; o_[dt][j] = O[q = q0+4g+j][d = lo+16dt]
    const int bb = bh >> 2, h = bh & 3;
    #pragma unroll
    for (int j = 0; j < 4; ++j) {
        float rl = __builtin_amdgcn_rcpf(ls[j]);
        int row = q0 + 4 * g + j;
        #pragma unroll
        for (int dt = 0; dt < 2; ++dt) {
            int e = h * 32 + lo + 16 * dt;
            float val = o_[dt][j] * rl;
            AO[((long)bb * N_SEQ + row) * 128 + e] =
                __builtin_bit_cast(unsigned short, (__bf16)val);
        }
    }
}

// ---------------- Kernel 3: output projection (fp32 GEMM + bias) ----------------
__global__ __launch_bounds__(256) void proj_kernel(
    const unsigned short* __restrict__ ain, const float* __restrict__ Wp,
    const float* __restrict__ bp, float* __restrict__ out)
{
    __shared__ __align__(16) float xT[128][36];
    const int tid = threadIdx.x;
    const long r0 = (long)blockIdx.x * 32;
    #pragma unroll
    for (int i = 0; i < 2; ++i) {
        int idx = i * 256 + tid;                 // 512 x u16x8
        int row = idx >> 4, kc = (idx & 15) * 8;
        u16x8 v = *(const u16x8*)&ain[(r0 + row) * 128 + kc];
        #pragma unroll
        for (int e = 0; e < 8; ++e) xT[kc + e][row] = bf2f(v[e]);
    }
    __syncthreads();
    const int r8 = (tid >> 6) * 8;
    const int c  = tid & 63;
    float acc0[8], acc1[8];
    #pragma unroll
    for (int r = 0; r < 8; ++r) { acc0[r] = 0.f; acc1[r] = 0.f; }
    for (int k = 0; k < 128; ++k) {
        f32x4 a0 = *(const f32x4*)&xT[k][r8];
        f32x4 a1 = *(const f32x4*)&xT[k][r8 + 4];
        float xr[8] = {a0[0],a0[1],a0[2],a0[3],a1[0],a1[1],a1[2],a1[3]};
        float w0 = Wp[k * 128 + c];
        float w1 = Wp[k * 128 + c + 64];
        #pragma unroll
        for (int r = 0; r < 8; ++r) {
            acc0[r] = fmaf(xr[r], w0, acc0[r]);
            acc1[r] = fmaf(xr[r], w1, acc1[r]);
        }
    }
    float b0 = bp[c], b1 = bp[c + 64];
    #pragma unroll
    for (int r = 0; r < 8; ++r) {
        long n = r0 + r8 + r;
        out[n * 128 + c]      = acc0[r] + b0;
        out[n * 128 + c + 64] = acc1[r] + b1;
    }
}

extern "C" void kernel_launch(void* const* d_in, const int* in_sizes, int n_in,
                              void* d_out, int out_size, void* d_ws, size_t ws_size,
                              hipStream_t stream)
{
    const float* x  = (const float*)d_in[0];
    const float* Wq = (const float*)d_in[1];
    const float* bq = (const float*)d_in[2];
    const float* Wp = (const float*)d_in[3];
    const float* bp = (const float*)d_in[4];
    float* out = (float*)d_out;

    // workspace: Q (4MB) | KF (4MB) | VF (4MB) | attn-out (4MB), all bf16
    unsigned short* Qw  = (unsigned short*)d_ws;
    unsigned short* KFw = Qw  + (size_t)16 * 4096 * 32;
    unsigned short* VFw = KFw + (size_t)16 * 4096 * 32;
    unsigned short* AOw = VFw + (size_t)16 * 4096 * 32;

    qkv_kernel<<<512, 256, 0, stream>>>(x, Wq, bq, Qw, KFw, VFw);
    attn_kernel<<<1024, 256, 0, stream>>>(Qw, KFw, VFw, AOw);
    proj_kernel<<<512, 256, 0, stream>>>(AOw, Wp, bp, out);
}

// Round 7
// 109.505 us; speedup vs baseline: 1.0595x; 1.0595x over previous
//
#include <hip/hip_runtime.h>
#include <stdint.h>

#define N_SEQ 4096

typedef float f32x4 __attribute__((ext_vector_type(4)));
typedef float f32x2 __attribute__((ext_vector_type(2)));
typedef unsigned short u16x8 __attribute__((ext_vector_type(8)));
typedef unsigned short u16x4 __attribute__((ext_vector_type(4)));
typedef unsigned int u32x2 __attribute__((ext_vector_type(2)));
typedef __bf16 bf16x8 __attribute__((ext_vector_type(8)));

static __device__ __forceinline__ float bf2f(unsigned short u) {
    unsigned v = ((unsigned)u) << 16;
    return __builtin_bit_cast(float, v);
}

// ---------------- Kernel 1: QKV projection (fp32 GEMM, bf16 out) ----------------
// (round-4/6 proven version, verbatim)
// Q  -> natural [bh][n][32], PRE-SCALED by SL = (1/sqrt(128))*log2(e)
// KF -> fragment-ready: KF[((bh*64+t)*4+ct)*512 + l*8 + i] = K[bh][64t+(l&15)+16ct][(l>>4)*8+i]
// VF -> fragment-ready, kv LINEAR: VF[(((bh*64+t)*2+kk)*2+dt)*512 + l*8 + i]
//       = V[bh][64t+kv][(l&15)+16dt], kv = kk*32 + (l>>4)*8 + i
__global__ __launch_bounds__(256) void qkv_kernel(
    const float* __restrict__ x, const float* __restrict__ Wq,
    const float* __restrict__ bq, unsigned short* __restrict__ Qo,
    unsigned short* __restrict__ KFo, unsigned short* __restrict__ VFo)
{
    __shared__ __align__(16) float xT[128][36];   // [k][row]
    const int tid = threadIdx.x;
    const long r0 = (long)blockIdx.x * 32;
    const float SL = (float)(0.08838834764831845 * 1.4426950408889634);
    #pragma unroll
    for (int i = 0; i < 4; ++i) {
        int idx = i * 256 + tid;                   // 1024 float4 tiles
        int row = idx >> 5, kc = (idx & 31) * 4;
        f32x4 v = *(const f32x4*)&x[(r0 + row) * 128 + kc];
        xT[kc + 0][row] = v[0]; xT[kc + 1][row] = v[1];
        xT[kc + 2][row] = v[2]; xT[kc + 3][row] = v[3];
    }
    __syncthreads();
    const int r8 = (tid >> 6) * 8;    // 8-row group
    const int c6 = (tid & 63) * 6;    // 6 consecutive cols
    float acc[6][8];
    #pragma unroll
    for (int j = 0; j < 6; ++j)
        #pragma unroll
        for (int r = 0; r < 8; ++r) acc[j][r] = 0.f;

    for (int k = 0; k < 128; ++k) {
        f32x4 a0 = *(const f32x4*)&xT[k][r8];      // wave-uniform broadcast
        f32x4 a1 = *(const f32x4*)&xT[k][r8 + 4];
        float xr[8] = {a0[0],a0[1],a0[2],a0[3],a1[0],a1[1],a1[2],a1[3]};
        float wv[6];
        #pragma unroll
        for (int u = 0; u < 3; ++u) {
            f32x2 wp = *(const f32x2*)&Wq[k * 384 + c6 + 2 * u];
            wv[2*u] = wp[0]; wv[2*u+1] = wp[1];
        }
        #pragma unroll
        for (int j = 0; j < 6; ++j)
            #pragma unroll
            for (int r = 0; r < 8; ++r) acc[j][r] = fmaf(xr[r], wv[j], acc[j][r]);
    }
    #pragma unroll
    for (int j = 0; j < 6; ++j) {
        int col = c6 + j;
        int h = col / 96, rem = col % 96;
        int d = rem / 3, s = rem % 3;
        float bias = bq[col];
        #pragma unroll
        for (int r = 0; r < 8; ++r) {
            long n = r0 + r8 + r;
            int bb = (int)(n >> 12), nn = (int)(n & 4095);
            int bh = bb * 4 + h;
            int t = nn >> 6, kvi = nn & 63;
            float val = acc[j][r] + bias;
            if (s == 0) {
                unsigned short bits = __builtin_bit_cast(unsigned short, (__bf16)(val * SL));
                Qo[((long)bh * 4096 + nn) * 32 + d] = bits;
            } else if (s == 1) {
                unsigned short bits = __builtin_bit_cast(unsigned short, (__bf16)val);
                int ct = kvi >> 4, lo16 = kvi & 15;
                int gg = d >> 3, ii = d & 7;
                int l = gg * 16 + lo16;
                KFo[(long)(((bh * 64 + t) * 4 + ct) * 512) + l * 8 + ii] = bits;
            } else {
                unsigned short bits = __builtin_bit_cast(unsigned short, (__bf16)val);
                int kk = kvi >> 5, lg = (kvi >> 3) & 3, ii = kvi & 7;
                int l = lg * 16 + (d & 15);
                int dt = d >> 4;
                VFo[(long)((((bh * 64 + t) * 2 + kk) * 2 + dt) * 512) + l * 8 + ii] = bits;
            }
        }
    }
}

// ---------------- Kernel 2: flash attention, 32 q-rows/wave + kv-split x2 ----------------
// BODY numerics identical to round-4 proven kernel. Block = 4 waves:
// wave w: q-subtile (w&1) [32 rows], kv-half (w>>1) [32 tiles of 64].
// No-max softmax => partial (o, ls) add linearly across kv-halves.
#define MFMA16 __builtin_amdgcn_mfma_f32_16x16x32_bf16

__global__ __launch_bounds__(256, 4) void attn_kernel(
    const unsigned short* __restrict__ Q, const unsigned short* __restrict__ KF,
    const unsigned short* __restrict__ VF, unsigned short* __restrict__ AO)
{
    __shared__ __align__(16) unsigned short P_lds[4][2][2048]; // per-wave dbuf P (32x64)

    const int tid = threadIdx.x, lane = tid & 63, w = tid >> 6;
    const int g = lane >> 4, lo = lane & 15;
    const int wq = w & 1, wh = w >> 1;

    // bijective XCD swizzle over 1024 blocks: each XCD owns 2 consecutive bh
    const int bid = blockIdx.x;
    const int vid = (bid & 7) * 128 + (bid >> 3);
    const int qi = vid & 63, bh = vid >> 6;
    const int q0 = qi * 64 + wq * 32;

    bf16x8 qf[2];
    #pragma unroll
    for (int rt = 0; rt < 2; ++rt) {
        const unsigned short* p = Q + ((long)bh * 4096 + q0 + rt * 16 + lo) * 32 + g * 8;
        qf[rt] = __builtin_bit_cast(bf16x8, *(const u16x8*)p);
    }
    bf16x8 onesf;
    {
        u16x8 ou = {0x3F80,0x3F80,0x3F80,0x3F80,0x3F80,0x3F80,0x3F80,0x3F80};
        onesf = __builtin_bit_cast(bf16x8, ou);
    }
    const f32x4 zf = {0.f, 0.f, 0.f, 0.f};
    f32x4 o_[2][2] = {{zf, zf}, {zf, zf}};
    f32x4 ls[2]    = {zf, zf};

    // P LDS layout: P[q][kv] at short-offset q*64 + (((kv>>3) ^ (q&7))*8) + (kv&7)
    // Swapped QK^T D-layout: s_[rt][ct][j] = S[q = 16rt + lo][kv = 16ct + 4g + j]
    int woff[2][4], roff[2][2];
    #pragma unroll
    for (int qt = 0; qt < 2; ++qt) {
        int q = lo + 16 * qt;
        #pragma unroll
        for (int ct = 0; ct < 4; ++ct) {
            int kvb = 16 * ct + 4 * g;
            woff[qt][ct] = q * 64 + (((kvb >> 3) ^ (q & 7)) * 8) + ((kvb >> 2) & 1) * 4;
        }
    }
    #pragma unroll
    for (int rt = 0; rt < 2; ++rt) {
        int q = lo + 16 * rt;
        #pragma unroll
        for (int kk = 0; kk < 2; ++kk)
            roff[rt][kk] = q * 64 + ((((4 * kk) + g) ^ (q & 7)) * 8);
    }
    unsigned short* B0 = &P_lds[w][0][0];
    unsigned short* B1 = &P_lds[w][1][0];

    const u16x8* kp = (const u16x8*)KF + ((long)bh * 64 + wh * 32) * 256 + lane;
    const u16x8* vp = (const u16x8*)VF + ((long)bh * 64 + wh * 32) * 256 + lane;

    u16x8 K0[4], K1[4], V0[4], V1[4];
    #pragma unroll
    for (int i = 0; i < 4; ++i) K0[i] = kp[i * 64];   // K(first tile of half)
    kp += 256;

// iteration t: prefetch K(t+1)->KN, V(t)->VC; read P(t-1) from BR; QK(t) with KC;
// PV(t-1) with VP; softmax(t) -> BW.
#define BODY(KC, KN, VP, VC, BW, BR, DOPV) do {                                \
    _Pragma("unroll")                                                          \
    for (int i = 0; i < 4; ++i) KN[i] = kp[i * 64];                            \
    kp += 256;                                                                 \
    _Pragma("unroll")                                                          \
    for (int i = 0; i < 4; ++i) VC[i] = vp[i * 64];                            \
    vp += 256;                                                                 \
    u16x8 pa_[2][2];                                                           \
    if (DOPV) {                                                                \
        _Pragma("unroll")                                                      \
        for (int kk = 0; kk < 2; ++kk)                                         \
            _Pragma("unroll")                                                  \
            for (int rt = 0; rt < 2; ++rt)                                     \
                pa_[kk][rt] = *(const u16x8*)&BR[roff[rt][kk]];                \
    }                                                                          \
    f32x4 s_[2][4];                                                            \
    _Pragma("unroll")                                                          \
    for (int ct = 0; ct < 4; ++ct) {                                           \
        bf16x8 kfr = __builtin_bit_cast(bf16x8, KC[ct]);                       \
        s_[0][ct] = MFMA16(kfr, qf[0], zf, 0, 0, 0);                           \
        s_[1][ct] = MFMA16(kfr, qf[1], zf, 0, 0, 0);                           \
    }                                                                          \
    if (DOPV) {                                                                \
        _Pragma("unroll")                                                      \
        for (int kk = 0; kk < 2; ++kk)                                         \
            _Pragma("unroll")                                                  \
            for (int rt = 0; rt < 2; ++rt) {                                   \
                bf16x8 paf = __builtin_bit_cast(bf16x8, pa_[kk][rt]);          \
                ls[rt] = MFMA16(paf, onesf, ls[rt], 0, 0, 0);                  \
                o_[rt][0] = MFMA16(paf, __builtin_bit_cast(bf16x8, VP[kk*2+0]),\
                                   o_[rt][0], 0, 0, 0);                        \
                o_[rt][1] = MFMA16(paf, __builtin_bit_cast(bf16x8, VP[kk*2+1]),\
                                   o_[rt][1], 0, 0, 0);                        \
            }                                                                  \
    }                                                                          \
    _Pragma("unroll")                                                          \
    for (int qt = 0; qt < 2; ++qt)                                             \
        _Pragma("unroll")                                                      \
        for (int ct = 0; ct < 4; ++ct) {                                       \
            unsigned b0 = __builtin_bit_cast(unsigned,                         \
                __builtin_amdgcn_exp2f(s_[qt][ct][0])) + 0x8000u;              \
            unsigned b1 = __builtin_bit_cast(unsigned,                         \
                __builtin_amdgcn_exp2f(s_[qt][ct][1])) + 0x8000u;              \
            unsigned b2 = __builtin_bit_cast(unsigned,                         \
                __builtin_amdgcn_exp2f(s_[qt][ct][2])) + 0x8000u;              \
            unsigned b3 = __builtin_bit_cast(unsigned,                         \
                __builtin_amdgcn_exp2f(s_[qt][ct][3])) + 0x8000u;              \
            u32x2 wv_;                                                         \
            wv_[0] = __builtin_amdgcn_perm(b1, b0, 0x07060302u);               \
            wv_[1] = __builtin_amdgcn_perm(b3, b2, 0x07060302u);               \
            *(u16x4*)&BW[woff[qt][ct]] = __builtin_bit_cast(u16x4, wv_);       \
        }                                                                      \
    __builtin_amdgcn_sched_barrier(0);                                         \
} while (0)

    BODY(K0, K1, V1, V0, B0, B1, 0);            // t = 0 of this half (no PV yet)
    #pragma unroll 1
    for (int t = 1; t < 31; t += 2) {
        BODY(K1, K0, V0, V1, B1, B0, 1);        // odd t
        BODY(K0, K1, V1, V0, B0, B1, 1);        // even t+1
    }
    BODY(K1, K0, V0, V1, B1, B0, 1);            // t = 31 (prefetch overshoots: in-bounds ws, unused)
#undef BODY

    // final PV(last): P in B1, V in V1
    #pragma unroll
    for (int kk = 0; kk < 2; ++kk)
        #pragma unroll
        for (int rt = 0; rt < 2; ++rt) {
            bf16x8 paf = __builtin_bit_cast(bf16x8, *(const u16x8*)&B1[roff[rt][kk]]);
            ls[rt] = MFMA16(paf, onesf, ls[rt], 0, 0, 0);
            o_[rt][0] = MFMA16(paf, __builtin_bit_cast(bf16x8, V1[kk*2+0]), o_[rt][0], 0, 0, 0);
            o_[rt][1] = MFMA16(paf, __builtin_bit_cast(bf16x8, V1[kk*2+1]), o_[rt][1], 0, 0, 0);
        }

    // ---- combine kv-halves (partials additive: no-max softmax) ----
    __syncthreads();                      // all P_lds reads done before reuse as scratch
    float* sc = (float*)&P_lds[0][0][0];  // 2 pairs x 64 lanes x 24 f32 = 12 KB
    float* myp = sc + (wq * 64 + lane) * 24;
    if (wh == 1) {
        #pragma unroll
        for (int rt = 0; rt < 2; ++rt)
            #pragma unroll
            for (int dt = 0; dt < 2; ++dt)
                *(f32x4*)&myp[(rt * 2 + dt) * 4] = o_[rt][dt];
        *(f32x4*)&myp[16] = ls[0];
        *(f32x4*)&myp[20] = ls[1];
    }
    __syncthreads();
    if (wh == 0) {
        #pragma unroll
        for (int rt = 0; rt < 2; ++rt) {
            #pragma unroll
            for (int dt = 0; dt < 2; ++dt)
                o_[rt][dt] += *(const f32x4*)&myp[(rt * 2 + dt) * 4];
            ls[rt] += *(const f32x4*)&myp[16 + rt * 4];
        }
        // epilogue: AO[b][n][h*32+d] bf16
        const int bb = bh >> 2, h = bh & 3;
        #pragma unroll
        for (int rt = 0; rt < 2; ++rt)
            #pragma unroll
            for (int j = 0; j < 4; ++j) {
                float rl = __builtin_amdgcn_rcpf(ls[rt][j]);
                int row = q0 + rt * 16 + 4 * g + j;
                #pragma unroll
                for (int dt = 0; dt < 2; ++dt) {
                    int e = h * 32 + lo + 16 * dt;
                    float val = o_[rt][dt][j] * rl;
                    AO[((long)bb * N_SEQ + row) * 128 + e] =
                        __builtin_bit_cast(unsigned short, (__bf16)val);
                }
            }
    }
}

// ---------------- Kernel 3: output projection (fp32 GEMM + bias) ----------------
__global__ __launch_bounds__(256) void proj_kernel(
    const unsigned short* __restrict__ ain, const float* __restrict__ Wp,
    const float* __restrict__ bp, float* __restrict__ out)
{
    __shared__ __align__(16) float xT[128][36];
    const int tid = threadIdx.x;
    const long r0 = (long)blockIdx.x * 32;
    #pragma unroll
    for (int i = 0; i < 2; ++i) {
        int idx = i * 256 + tid;                 // 512 x u16x8
        int row = idx >> 4, kc = (idx & 15) * 8;
        u16x8 v = *(const u16x8*)&ain[(r0 + row) * 128 + kc];
        #pragma unroll
        for (int e = 0; e < 8; ++e) xT[kc + e][row] = bf2f(v[e]);
    }
    __syncthreads();
    const int r8 = (tid >> 6) * 8;
    const int c  = tid & 63;
    float acc0[8], acc1[8];
    #pragma unroll
    for (int r = 0; r < 8; ++r) { acc0[r] = 0.f; acc1[r] = 0.f; }
    for (int k = 0; k < 128; ++k) {
        f32x4 a0 = *(const f32x4*)&xT[k][r8];
        f32x4 a1 = *(const f32x4*)&xT[k][r8 + 4];
        float xr[8] = {a0[0],a0[1],a0[2],a0[3],a1[0],a1[1],a1[2],a1[3]};
        float w0 = Wp[k * 128 + c];
        float w1 = Wp[k * 128 + c + 64];
        #pragma unroll
        for (int r = 0; r < 8; ++r) {
            acc0[r] = fmaf(xr[r], w0, acc0[r]);
            acc1[r] = fmaf(xr[r], w1, acc1[r]);
        }
    }
    float b0 = bp[c], b1 = bp[c + 64];
    #pragma unroll
    for (int r = 0; r < 8; ++r) {
        long n = r0 + r8 + r;
        out[n * 128 + c]      = acc0[r] + b0;
        out[n * 128 + c + 64] = acc1[r] + b1;
    }
}

extern "C" void kernel_launch(void* const* d_in, const int* in_sizes, int n_in,
                              void* d_out, int out_size, void* d_ws, size_t ws_size,
                              hipStream_t stream)
{
    const float* x  = (const float*)d_in[0];
    const float* Wq = (const float*)d_in[1];
    const float* bq = (const float*)d_in[2];
    const float* Wp = (const float*)d_in[3];
    const float* bp = (const float*)d_in[4];
    float* out = (float*)d_out;

    // workspace: Q (4MB) | KF (4MB) | VF (4MB) | attn-out (4MB), all bf16
    unsigned short* Qw  = (unsigned short*)d_ws;
    unsigned short* KFw = Qw  + (size_t)16 * 4096 * 32;
    unsigned short* VFw = KFw + (size_t)16 * 4096 * 32;
    unsigned short* AOw = VFw + (size_t)16 * 4096 * 32;

    qkv_kernel<<<512, 256, 0, stream>>>(x, Wq, bq, Qw, KFw, VFw);
    attn_kernel<<<1024, 256, 0, stream>>>(Qw, KFw, VFw, AOw);
    proj_kernel<<<512, 256, 0, stream>>>(AOw, Wp, bp, out);
}